// Round 9
// baseline (1437.285 us; speedup 1.0000x reference)
//
#include <hip/hip_runtime.h>
#include <math.h>

// Sizes: B=16, H=128, W=128, C=64, MODES=16, SCHMIDT=8, N_LAYERS=4
// h buffer: 16*128*128*64 = 16,777,216 floats (67 MB), updated in place per layer.

#define TWO_PI_128 0.049087385212340517f   // 2*pi/128

// gelu(v) = v * (1 - 1/(e^{2u} + 1)), u = 0.79788456 v (1 + 0.044715 v^2)
__device__ __forceinline__ float gelu_f(float v) {
  float ex = 1.5957691216057308f * v * fmaf(0.044715f, v * v, 1.0f);  // 2u
  float e = __expf(fminf(ex, 30.0f));      // clamp: avoid inf -> NaN in rcp
  float r = __builtin_amdgcn_rcpf(e + 1.0f);
  return fmaf(-v, r, v);
}

// h[pix][c4..c4+3] = x[pix][:3] @ w + b   (float4 over c)
__global__ __launch_bounds__(256) void k_fc_in(const float* __restrict__ x,
    const float* __restrict__ w, const float* __restrict__ b,
    float* __restrict__ h) {
  int t = blockIdx.x * 256 + threadIdx.x;   // over NPIX*16
  int pix = t >> 4, c4 = (t & 15) << 2;
  float x0 = x[pix * 3], x1 = x[pix * 3 + 1], x2 = x[pix * 3 + 2];
  float4 acc = *(const float4*)&b[c4];
  float4 w0 = *(const float4*)&w[c4];
  float4 w1 = *(const float4*)&w[64 + c4];
  float4 w2 = *(const float4*)&w[128 + c4];
  acc.x = fmaf(x2, w2.x, fmaf(x1, w1.x, fmaf(x0, w0.x, acc.x)));
  acc.y = fmaf(x2, w2.y, fmaf(x1, w1.y, fmaf(x0, w0.y, acc.y)));
  acc.z = fmaf(x2, w2.z, fmaf(x1, w1.z, fmaf(x0, w0.z, acc.z)));
  acc.w = fmaf(x2, w2.w, fmaf(x1, w1.w, fmaf(x0, w0.w, acc.w)));
  *(float4*)&h[(size_t)pix * 64 + c4] = acc;
}

// Fold Schmidt sum + 1/sqrt(8) + 1/(128*128) into complex weight,
// laid out for GEMM: Br/Bi[(n*64+c)*1024 + (m*64+o)]
__global__ __launch_bounds__(256) void k_prep(const float* __restrict__ wr,
    const float* __restrict__ wi, float* __restrict__ Br, float* __restrict__ Bi) {
  int t = blockIdx.x * 256 + threadIdx.x;     // linear over (m,n,c,o), o innermost
  int o = t & 63, c = (t >> 6) & 63, n = (t >> 12) & 15, m = t >> 16;
  const float4* pr = (const float4*)(wr) + (size_t)t * 2;
  float4 a = pr[0], d = pr[1];
  float sr = ((a.x + a.y) + (a.z + a.w)) + ((d.x + d.y) + (d.z + d.w));
  const float4* pi = (const float4*)(wi) + (size_t)t * 2;
  a = pi[0]; d = pi[1];
  float si = ((a.x + a.y) + (a.z + a.w)) + ((d.x + d.y) + (d.z + d.w));
  const float scale = 0.35355339059327373f / 16384.0f;  // 1/(sqrt(8)*128*128)
  int k = n * 64 + c, j = m * 64 + o;
  Br[k * 1024 + j] = sr * scale;
  Bi[k * 1024 + j] = si * scale;
}

// Forward truncated DFT along y (W axis): A1[b][x][ky][c], ky<16
// radix-4 sub-accumulation: one twiddle recurrence per 4 samples.
__global__ __launch_bounds__(256) void k_dft_y(const float* __restrict__ h,
                                               float2* __restrict__ A1) {
  __shared__ float sh[128 * 64];
  int bx = blockIdx.x;                        // b*128 + x
  const float* src = h + (size_t)bx * 8192;
  for (int i = threadIdx.x; i < 2048; i += 256)
    *(float4*)&sh[i * 4] = *(const float4*)&src[i * 4];
  __syncthreads();
  int c = threadIdx.x & 63, kg = threadIdx.x >> 6;
  float s4r[4][4], s4i[4][4];                 // [q][p]
  float w4r[4], w4i[4], c4t[4], s4t[4];
  #pragma unroll
  for (int q = 0; q < 4; ++q) {
    int ky = kg + 4 * q;
    __sincosf(-TWO_PI_128 * 4.0f * (float)ky, &s4t[q], &c4t[q]);
    w4r[q] = 1.f; w4i[q] = 0.f;
    #pragma unroll
    for (int p = 0; p < 4; ++p) { s4r[q][p] = 0.f; s4i[q][p] = 0.f; }
  }
  for (int m = 0; m < 32; ++m) {
    float hv[4];
    #pragma unroll
    for (int p = 0; p < 4; ++p) hv[p] = sh[(4 * m + p) * 64 + c];
    #pragma unroll
    for (int q = 0; q < 4; ++q) {
      #pragma unroll
      for (int p = 0; p < 4; ++p) {
        s4r[q][p] = fmaf(hv[p], w4r[q], s4r[q][p]);
        s4i[q][p] = fmaf(hv[p], w4i[q], s4i[q][p]);
      }
      float nw = w4r[q] * c4t[q] - w4i[q] * s4t[q];
      w4i[q] = fmaf(w4i[q], c4t[q], w4r[q] * s4t[q]);
      w4r[q] = nw;
    }
  }
  #pragma unroll
  for (int q = 0; q < 4; ++q) {
    int ky = kg + 4 * q;
    float s1, c1;
    __sincosf(-TWO_PI_128 * (float)ky, &s1, &c1);
    float sr = s4r[q][0], si = s4i[q][0];
    float wr_ = c1, wi_ = s1;
    #pragma unroll
    for (int p = 1; p < 4; ++p) {
      sr = fmaf(s4r[q][p], wr_, sr); sr = fmaf(-s4i[q][p], wi_, sr);
      si = fmaf(s4r[q][p], wi_, si); si = fmaf(s4i[q][p], wr_, si);
      float nw = wr_ * c1 - wi_ * s1;
      wi_ = fmaf(wi_, c1, wr_ * s1);
      wr_ = nw;
    }
    A1[((size_t)bx * 16 + ky) * 64 + c] = make_float2(sr, si);
  }
}

// Forward truncated DFT along x (H axis): rows (b*16+kx), cols (ky*64+c)
__global__ __launch_bounds__(256) void k_dft_x(const float2* __restrict__ A1,
    float* __restrict__ Ar, float* __restrict__ Ai) {
  __shared__ float2 sh[128 * 32];
  int b = blockIdx.x, ky = blockIdx.y, ch = blockIdx.z;
  int c0 = ch * 32;
  for (int i = threadIdx.x; i < 2048; i += 256) {
    int xx = i >> 4, u = (i & 15) * 2;
    *(float4*)&sh[xx * 32 + u] =
        *(const float4*)&A1[(((size_t)b * 128 + xx) * 16 + ky) * 64 + c0 + u];
  }
  __syncthreads();
  int cl = threadIdx.x & 31, kxg = threadIdx.x >> 5;
  float cs[2], sn[2], wr_[2], wi_[2], sr[2], si[2];
  #pragma unroll
  for (int q = 0; q < 2; ++q) {
    int kx = kxg + 8 * q;
    __sincosf(-TWO_PI_128 * (float)kx, &sn[q], &cs[q]);
    wr_[q] = 1.f; wi_[q] = 0.f; sr[q] = 0.f; si[q] = 0.f;
  }
  for (int xx = 0; xx < 128; ++xx) {
    float2 v = sh[xx * 32 + cl];
    #pragma unroll
    for (int q = 0; q < 2; ++q) {
      sr[q] = fmaf(v.x, wr_[q], sr[q]); sr[q] = fmaf(-v.y, wi_[q], sr[q]);
      si[q] = fmaf(v.x, wi_[q], si[q]); si[q] = fmaf(v.y, wr_[q], si[q]);
      float nw = wr_[q] * cs[q] - wi_[q] * sn[q];
      wi_[q] = fmaf(wi_[q], cs[q], wr_[q] * sn[q]);
      wr_[q] = nw;
    }
  }
  #pragma unroll
  for (int q = 0; q < 2; ++q) {
    int kx = kxg + 8 * q;
    int row = b * 16 + kx, col = ky * 64 + c0 + cl;
    Ar[row * 1024 + col] = sr[q];
    Ai[row * 1024 + col] = si[q];
  }
}

#define CMAC(cr, ci, ax, ay, bx, by)                 \
  cr = fmaf(ax, bx, cr); cr = fmaf(-(ay), by, cr);   \
  ci = fmaf(ax, by, ci); ci = fmaf(ay, bx, ci);

// Complex GEMM: C[256][1024] = A[256][1024] * B[1024][1024], K-split 8.
// 64x64 C-tile / 4x4 acc; partials z=0 -> Cp, z=1..7 -> A1 space; k_csum sums.
// Single barrier per K-tile (classic double-buffer); coalesced B reads/stores.
__global__ __launch_bounds__(256) void k_gemm(const float* __restrict__ Ar,
    const float* __restrict__ Ai, const float* __restrict__ Br,
    const float* __restrict__ Bi, float2* __restrict__ Cp,
    float2* __restrict__ Pp) {
  __shared__ float2 As[2][64][34];   // [row][kk] 34816 B
  __shared__ float2 Bs[2][32][66];   // [kk][j]   33792 B
  int t = threadIdx.x;
  int tx = t & 15, ty = t >> 4;
  int col0 = blockIdx.x * 64, row0 = blockIdx.y * 64, kb0 = blockIdx.z * 128;
  int ra = t >> 2, ka8 = (t & 3) * 8;      // A stage: row ra, k ka8..+7
  int rb = t >> 3, jb8 = (t & 7) * 8;      // B stage: k rb, j jb8..+7
  float4 arv0, arv1, aiv0, aiv1, brv0, brv1, biv0, biv1;
  float cr[4][4] = {{0,0,0,0},{0,0,0,0},{0,0,0,0},{0,0,0,0}};
  float ci[4][4] = {{0,0,0,0},{0,0,0,0},{0,0,0,0},{0,0,0,0}};

  auto ldT = [&](int k0) {
    int g = (row0 + ra) * 1024 + k0 + ka8;
    arv0 = *(const float4*)&Ar[g]; arv1 = *(const float4*)&Ar[g + 4];
    aiv0 = *(const float4*)&Ai[g]; aiv1 = *(const float4*)&Ai[g + 4];
    int gb = (k0 + rb) * 1024 + col0 + jb8;
    brv0 = *(const float4*)&Br[gb]; brv1 = *(const float4*)&Br[gb + 4];
    biv0 = *(const float4*)&Bi[gb]; biv1 = *(const float4*)&Bi[gb + 4];
  };
  auto stT = [&](int buf) {
    *(float4*)&As[buf][ra][ka8]     = make_float4(arv0.x, aiv0.x, arv0.y, aiv0.y);
    *(float4*)&As[buf][ra][ka8 + 2] = make_float4(arv0.z, aiv0.z, arv0.w, aiv0.w);
    *(float4*)&As[buf][ra][ka8 + 4] = make_float4(arv1.x, aiv1.x, arv1.y, aiv1.y);
    *(float4*)&As[buf][ra][ka8 + 6] = make_float4(arv1.z, aiv1.z, arv1.w, aiv1.w);
    *(float4*)&Bs[buf][rb][jb8]     = make_float4(brv0.x, biv0.x, brv0.y, biv0.y);
    *(float4*)&Bs[buf][rb][jb8 + 2] = make_float4(brv0.z, biv0.z, brv0.w, biv0.w);
    *(float4*)&Bs[buf][rb][jb8 + 4] = make_float4(brv1.x, biv1.x, brv1.y, biv1.y);
    *(float4*)&Bs[buf][rb][jb8 + 6] = make_float4(brv1.z, biv1.z, brv1.w, biv1.w);
  };

  ldT(kb0); stT(0);
  __syncthreads();
  for (int kt = 0; kt < 4; ++kt) {
    if (kt < 3) ldT(kb0 + (kt + 1) * 32);   // overlap next-tile loads w/ compute
    int cur = kt & 1;
    #pragma unroll 4
    for (int kk2 = 0; kk2 < 16; ++kk2) {
      float4 av[4];
      #pragma unroll
      for (int rr = 0; rr < 4; ++rr)
        av[rr] = *(const float4*)&As[cur][ty * 4 + rr][kk2 * 2];
      float2 b0[4], b1[4];
      #pragma unroll
      for (int jj = 0; jj < 4; ++jj) b0[jj] = Bs[cur][kk2 * 2][tx + jj * 16];
      #pragma unroll
      for (int jj = 0; jj < 4; ++jj) b1[jj] = Bs[cur][kk2 * 2 + 1][tx + jj * 16];
      #pragma unroll
      for (int rr = 0; rr < 4; ++rr) {
        #pragma unroll
        for (int jj = 0; jj < 4; ++jj) {
          CMAC(cr[rr][jj], ci[rr][jj], av[rr].x, av[rr].y, b0[jj].x, b0[jj].y)
          CMAC(cr[rr][jj], ci[rr][jj], av[rr].z, av[rr].w, b1[jj].x, b1[jj].y)
        }
      }
    }
    if (kt < 3) stT(cur ^ 1);   // safe w/o pre-barrier: cur^1 not read this iter
    __syncthreads();            // stT visible before next iter reads cur^1
  }
  float2* Co = (blockIdx.z == 0) ? Cp : Pp + (size_t)(blockIdx.z - 1) * 262144;
  #pragma unroll
  for (int rr = 0; rr < 4; ++rr) {
    int r = row0 + ty * 4 + rr;
    #pragma unroll
    for (int jj = 0; jj < 4; ++jj) {
      int j = col0 + tx + jj * 16;
      Co[(size_t)r * 1024 + j] = make_float2(cr[rr][jj], ci[rr][jj]);
    }
  }
}

// Reduce the 7 A1-space partials into Cp. 131072 float4 = grid 512.
__global__ __launch_bounds__(256) void k_csum(float2* __restrict__ Cp,
                                              const float2* __restrict__ Pp) {
  int i = blockIdx.x * 256 + threadIdx.x;
  float4* c0 = (float4*)Cp;
  float4 s = c0[i];
  #pragma unroll
  for (int z = 0; z < 7; ++z) {
    float4 v = ((const float4*)(Pp + (size_t)z * 262144))[i];
    s.x += v.x; s.y += v.y; s.z += v.z; s.w += v.w;
  }
  c0[i] = s;
}

// Inverse DFT along the W-frequency axis m -> y (Cp pre-summed by k_csum).
// T layout: [b][y][kx][c]
__global__ __launch_bounds__(256) void k_ifft_y(const float2* __restrict__ Cp,
                                                float2* __restrict__ T) {
  __shared__ float2 Cl[1024];
  int b = blockIdx.x >> 4, kx = blockIdx.x & 15;
  int row = b * 16 + kx;
  for (int i = threadIdx.x; i < 512; i += 256)
    *(float4*)&Cl[i * 2] = *(const float4*)&Cp[(size_t)row * 1024 + i * 2];
  __syncthreads();
  int c = threadIdx.x & 63, yg = threadIdx.x >> 6;
  for (int y = yg; y < 128; y += 4) {
    float snv, csv;
    __sincosf(TWO_PI_128 * (float)y, &snv, &csv);
    float wr_ = 1.f, wi_ = 0.f, sr = 0.f, si = 0.f;
    #pragma unroll
    for (int ky = 0; ky < 16; ++ky) {
      float2 v = Cl[ky * 64 + c];
      sr = fmaf(v.x, wr_, sr); sr = fmaf(-v.y, wi_, sr);
      si = fmaf(v.x, wi_, si); si = fmaf(v.y, wr_, si);
      float nw = wr_ * csv - wi_ * snv;
      wi_ = fmaf(wi_, csv, wr_ * snv);
      wr_ = nw;
    }
    T[(((size_t)b * 128 + y) * 16 + kx) * 64 + c] = make_float2(sr, si);
  }
}

// Fused: inverse DFT along kx -> x (real part) + pointwise h@ww + wb + gelu.
// Block (b,y): reads/writes exactly the h elements at fixed (b,y).
// v8: (a) x2's global hv loads double-buffered (k_final's proven hv/hn
// pattern) -- the 4 L3-latency loads per kq were consumed immediately at
// unroll 1, leaking ~500cy stalls at 4 waves/SIMD; (b) occupancy request
// 4 -> 6 blocks/CU (LDS 25.6 KB allows 6; VGPR ~76 fits 85/wave budget).
// Final dangling prefetch lands in A1's region of d_ws: in-bounds, unused.
__global__ __launch_bounds__(256, 6) void k_layer_out(const float* hin,
    const float2* __restrict__ T, const float* __restrict__ ww,
    const float* __restrict__ wb, float* hout) {
  __shared__ alignas(16) float wwT[64 * 68];
  __shared__ alignas(16) float2 Tl[1024];
  int b = blockIdx.x >> 7, y = blockIdx.x & 127;
  for (int i = threadIdx.x; i < 1024; i += 256) {
    int k = i >> 4, c4 = (i & 15) << 2;
    float4 v = *(const float4*)&ww[k * 64 + c4];
    wwT[(c4 + 0) * 68 + k] = v.x;
    wwT[(c4 + 1) * 68 + k] = v.y;
    wwT[(c4 + 2) * 68 + k] = v.z;
    wwT[(c4 + 3) * 68 + k] = v.w;
  }
  const float2* Tp = T + ((size_t)b * 128 + y) * 1024;
  for (int i = threadIdx.x; i < 512; i += 256)
    *(float4*)&Tl[i * 2] = *(const float4*)&Tp[i * 2];
  __syncthreads();
  int ct = threadIdx.x & 7, xg = threadIdx.x >> 3;  // c = ct+8cc, x = xg+32j
  float acc[4][8];
  #pragma unroll
  for (int cc = 0; cc < 8; ++cc) {
    float bv = wb[ct + 8 * cc];
    #pragma unroll
    for (int j = 0; j < 4; ++j) acc[j][cc] = bv;
  }
  // x1: real part of sum_kx T[kx][c] * e^{+2pi i kx x/128}
  #pragma unroll
  for (int kx = 0; kx < 16; ++kx) {
    float tr[8], ti[8];
    #pragma unroll
    for (int cc = 0; cc < 8; ++cc) {
      float2 v = Tl[kx * 64 + ct + 8 * cc];
      tr[cc] = v.x; ti[cc] = v.y;
    }
    float s0v, c0v;
    __sincosf(TWO_PI_128 * (float)(kx * xg), &s0v, &c0v);
    float wr_ = c0v, wi_ = s0v;
    #pragma unroll
    for (int j = 0; j < 4; ++j) {
      #pragma unroll
      for (int cc = 0; cc < 8; ++cc) {
        acc[j][cc] = fmaf(tr[cc], wr_, acc[j][cc]);
        acc[j][cc] = fmaf(-ti[cc], wi_, acc[j][cc]);
      }
      // rotate (wr,wi) by i^kx -- kx is unroll-constant, folds at compile time
      float owr = wr_, owi = wi_;
      if ((kx & 3) == 1)      { wr_ = -owi; wi_ =  owr; }
      else if ((kx & 3) == 2) { wr_ = -owr; wi_ = -owi; }
      else if ((kx & 3) == 3) { wr_ =  owi; wi_ = -owr; }
    }
  }
  // x2: h @ ww, h read from global (rows x = xg+32j at fixed y), double-buffered
  const float* hp = hin + (((size_t)b * 128 + xg) * 128 + y) * 64;
  float4 hv[4], hn[4];
  #pragma unroll
  for (int j = 0; j < 4; ++j) hv[j] = *(const float4*)&hp[(size_t)j * 262144];
  auto fmab = [&](const float4* H, int kq) {
    #pragma unroll
    for (int cc = 0; cc < 8; ++cc) {
      float4 wv = *(const float4*)&wwT[(ct + 8 * cc) * 68 + kq];
      #pragma unroll
      for (int j = 0; j < 4; ++j) {
        acc[j][cc] = fmaf(H[j].x, wv.x, acc[j][cc]);
        acc[j][cc] = fmaf(H[j].y, wv.y, acc[j][cc]);
        acc[j][cc] = fmaf(H[j].z, wv.z, acc[j][cc]);
        acc[j][cc] = fmaf(H[j].w, wv.w, acc[j][cc]);
      }
    }
  };
  #pragma unroll 1
  for (int kq = 0; kq < 64; kq += 8) {
    #pragma unroll
    for (int j = 0; j < 4; ++j)
      hn[j] = *(const float4*)&hp[(size_t)j * 262144 + kq + 4];
    fmab(hv, kq);
    #pragma unroll
    for (int j = 0; j < 4; ++j)   // last prefetch reads into A1 region: unused
      hv[j] = *(const float4*)&hp[(size_t)j * 262144 + kq + 8];
    fmab(hn, kq + 4);
  }
  __syncthreads();   // all hin reads drained (barrier waits vmcnt) before stores
  #pragma unroll
  for (int j = 0; j < 4; ++j) {
    int xx = xg + 32 * j;
    size_t base = (((size_t)b * 128 + xx) * 128 + y) * 64 + ct;
    #pragma unroll
    for (int cc = 0; cc < 8; ++cc)
      hout[base + 8 * cc] = gelu_f(acc[j][cc]);
  }
}

// Fused fc1 + gelu + fc2.  (round-2 structure, measured 81.6us at r7 clocks;
// byte-identical anchor kernel -- also the cross-round clock-noise gauge.)
__global__ __launch_bounds__(256) void k_final(const float* __restrict__ h,
    const float* __restrict__ w1, const float* __restrict__ b1,
    const float* __restrict__ w2, const float* __restrict__ b2,
    float* __restrict__ out) {
  __shared__ alignas(16) float w1T[128 * 68];   // w1T[j][k]
  __shared__ alignas(16) float hl[128 * 68];    // hl[r][k]
  __shared__ float b1s[128];
  __shared__ float w2s[128];
  for (int i = threadIdx.x; i < 8192; i += 256) {
    int k = i >> 7, j = i & 127;
    w1T[j * 68 + k] = w1[i];
  }
  if (threadIdx.x < 128) {
    b1s[threadIdx.x] = b1[threadIdx.x];
    w2s[threadIdx.x] = w2[threadIdx.x];
  }
  int r0 = blockIdx.x * 128;
  for (int i = threadIdx.x; i < 2048; i += 256) {
    int r = i >> 4, kq = (i & 15) * 4;          // coalesced float4 row loads
    float4 v = *(const float4*)&h[(size_t)(r0 + r) * 64 + kq];
    *(float4*)&hl[r * 68 + kq] = v;
  }
  __syncthreads();
  int jt = threadIdx.x & 15, rg = threadIdx.x >> 4;  // j = jt+16*cc, r = rg+16*ii
  float acc[8][8];   // [ii][cc]
  #pragma unroll
  for (int cc = 0; cc < 8; ++cc) {
    float bv = b1s[jt + 16 * cc];
    #pragma unroll
    for (int ii = 0; ii < 8; ++ii) acc[ii][cc] = bv;
  }
  #pragma unroll 1
  for (int kq = 0; kq < 64; kq += 4) {
    float4 hv[8];
    #pragma unroll
    for (int ii = 0; ii < 8; ++ii)
      hv[ii] = *(const float4*)&hl[(rg + 16 * ii) * 68 + kq];
    #pragma unroll
    for (int cc = 0; cc < 8; ++cc) {
      float4 wv = *(const float4*)&w1T[(jt + 16 * cc) * 68 + kq];
      #pragma unroll
      for (int ii = 0; ii < 8; ++ii) {
        acc[ii][cc] = fmaf(hv[ii].x, wv.x, acc[ii][cc]);
        acc[ii][cc] = fmaf(hv[ii].y, wv.y, acc[ii][cc]);
        acc[ii][cc] = fmaf(hv[ii].z, wv.z, acc[ii][cc]);
        acc[ii][cc] = fmaf(hv[ii].w, wv.w, acc[ii][cc]);
      }
    }
  }
  float b2v = b2[0];
  #pragma unroll
  for (int ii = 0; ii < 8; ++ii) {
    float part = 0.f;
    #pragma unroll
    for (int cc = 0; cc < 8; ++cc)
      part = fmaf(gelu_f(acc[ii][cc]), w2s[jt + 16 * cc], part);
    part += __shfl_xor(part, 1, 64);
    part += __shfl_xor(part, 2, 64);
    part += __shfl_xor(part, 4, 64);
    part += __shfl_xor(part, 8, 64);
    if (jt == 0) out[r0 + rg + 16 * ii] = part + b2v;
  }
}

extern "C" void kernel_launch(void* const* d_in, const int* in_sizes, int n_in,
                              void* d_out, int out_size, void* d_ws, size_t ws_size,
                              hipStream_t stream) {
  (void)in_sizes; (void)n_in; (void)out_size; (void)ws_size;
  const float* x      = (const float*)d_in[0];
  const float* fcin_w = (const float*)d_in[1];
  const float* fcin_b = (const float*)d_in[2];
  const float* wr     = (const float*)d_in[3];
  const float* wi     = (const float*)d_in[4];
  const float* ww     = (const float*)d_in[5];
  const float* wb     = (const float*)d_in[6];
  const float* fc1_w  = (const float*)d_in[7];
  const float* fc1_b  = (const float*)d_in[8];
  const float* fc2_w  = (const float*)d_in[9];
  const float* fc2_b  = (const float*)d_in[10];
  float* out = (float*)d_out;

  // workspace layout (floats): 96.5 MB total (within the validated 98.6 MB).
  // A1's 16 MB doubles as the GEMM partial buffer (z=1..7, 14 MB): A1 is dead
  // between k_dft_x (last read) and k_ifft_y (T write), and k_csum drains the
  // partials into Cp before k_ifft_y runs. Stream order serializes all of it.
  float*  hA = (float*)d_ws;              // 16,777,216
  float2* A1 = (float2*)(hA + 16777216);  // 2,097,152 float2 (A1 / T / partials)
  float*  Ar = (float*)(A1 + 2097152);    // 262,144
  float*  Ai = Ar + 262144;               // 262,144
  float*  Br = Ai + 262144;               // 1,048,576
  float*  Bi = Br + 1048576;              // 1,048,576
  float2* Cp = (float2*)(Bi + 1048576);   // 262,144 float2 (z=0 partial / sum)

  k_fc_in<<<16384, 256, 0, stream>>>(x, fcin_w, fcin_b, hA);
  for (int l = 0; l < 4; ++l) {
    k_prep<<<4096, 256, 0, stream>>>(wr + (size_t)l * 8388608,
                                     wi + (size_t)l * 8388608, Br, Bi);
    k_dft_y<<<2048, 256, 0, stream>>>(hA, A1);
    k_dft_x<<<dim3(16, 16, 2), 256, 0, stream>>>(A1, Ar, Ai);
    k_gemm<<<dim3(16, 4, 8), 256, 0, stream>>>(Ar, Ai, Br, Bi, Cp, A1);
    k_csum<<<512, 256, 0, stream>>>(Cp, A1);
    k_ifft_y<<<256, 256, 0, stream>>>(Cp, A1);     // A1 now holds T
    k_layer_out<<<2048, 256, 0, stream>>>(hA, A1, ww + (size_t)l * 4096,
                                          wb + (size_t)l * 64, hA);
  }
  k_final<<<2048, 256, 0, stream>>>(hA, fc1_w, fc1_b, fc2_w, fc2_b, out);
}

// Round 10
// 968.514 us; speedup vs baseline: 1.4840x; 1.4840x over previous
//
#include <hip/hip_runtime.h>
#include <math.h>

// Sizes: B=16, H=128, W=128, C=64, MODES=16, SCHMIDT=8, N_LAYERS=4
// h buffer: 16*128*128*64 = 16,777,216 floats (67 MB), updated in place per layer.

#define TWO_PI_128 0.049087385212340517f   // 2*pi/128

// gelu(v) = v * (1 - 1/(e^{2u} + 1)), u = 0.79788456 v (1 + 0.044715 v^2)
__device__ __forceinline__ float gelu_f(float v) {
  float ex = 1.5957691216057308f * v * fmaf(0.044715f, v * v, 1.0f);  // 2u
  float e = __expf(fminf(ex, 30.0f));      // clamp: avoid inf -> NaN in rcp
  float r = __builtin_amdgcn_rcpf(e + 1.0f);
  return fmaf(-v, r, v);
}

// h[pix][c4..c4+3] = x[pix][:3] @ w + b   (float4 over c)
__global__ __launch_bounds__(256) void k_fc_in(const float* __restrict__ x,
    const float* __restrict__ w, const float* __restrict__ b,
    float* __restrict__ h) {
  int t = blockIdx.x * 256 + threadIdx.x;   // over NPIX*16
  int pix = t >> 4, c4 = (t & 15) << 2;
  float x0 = x[pix * 3], x1 = x[pix * 3 + 1], x2 = x[pix * 3 + 2];
  float4 acc = *(const float4*)&b[c4];
  float4 w0 = *(const float4*)&w[c4];
  float4 w1 = *(const float4*)&w[64 + c4];
  float4 w2 = *(const float4*)&w[128 + c4];
  acc.x = fmaf(x2, w2.x, fmaf(x1, w1.x, fmaf(x0, w0.x, acc.x)));
  acc.y = fmaf(x2, w2.y, fmaf(x1, w1.y, fmaf(x0, w0.y, acc.y)));
  acc.z = fmaf(x2, w2.z, fmaf(x1, w1.z, fmaf(x0, w0.z, acc.z)));
  acc.w = fmaf(x2, w2.w, fmaf(x1, w1.w, fmaf(x0, w0.w, acc.w)));
  *(float4*)&h[(size_t)pix * 64 + c4] = acc;
}

// Fold Schmidt sum + 1/sqrt(8) + 1/(128*128) into complex weight,
// laid out for GEMM: Br/Bi[(n*64+c)*1024 + (m*64+o)]
__global__ __launch_bounds__(256) void k_prep(const float* __restrict__ wr,
    const float* __restrict__ wi, float* __restrict__ Br, float* __restrict__ Bi) {
  int t = blockIdx.x * 256 + threadIdx.x;     // linear over (m,n,c,o), o innermost
  int o = t & 63, c = (t >> 6) & 63, n = (t >> 12) & 15, m = t >> 16;
  const float4* pr = (const float4*)(wr) + (size_t)t * 2;
  float4 a = pr[0], d = pr[1];
  float sr = ((a.x + a.y) + (a.z + a.w)) + ((d.x + d.y) + (d.z + d.w));
  const float4* pi = (const float4*)(wi) + (size_t)t * 2;
  a = pi[0]; d = pi[1];
  float si = ((a.x + a.y) + (a.z + a.w)) + ((d.x + d.y) + (d.z + d.w));
  const float scale = 0.35355339059327373f / 16384.0f;  // 1/(sqrt(8)*128*128)
  int k = n * 64 + c, j = m * 64 + o;
  Br[k * 1024 + j] = sr * scale;
  Bi[k * 1024 + j] = si * scale;
}

// Forward truncated DFT along y (W axis): A1[b][x][ky][c], ky<16
// radix-4 sub-accumulation: one twiddle recurrence per 4 samples.
__global__ __launch_bounds__(256) void k_dft_y(const float* __restrict__ h,
                                               float2* __restrict__ A1) {
  __shared__ float sh[128 * 64];
  int bx = blockIdx.x;                        // b*128 + x
  const float* src = h + (size_t)bx * 8192;
  for (int i = threadIdx.x; i < 2048; i += 256)
    *(float4*)&sh[i * 4] = *(const float4*)&src[i * 4];
  __syncthreads();
  int c = threadIdx.x & 63, kg = threadIdx.x >> 6;
  float s4r[4][4], s4i[4][4];                 // [q][p]
  float w4r[4], w4i[4], c4t[4], s4t[4];
  #pragma unroll
  for (int q = 0; q < 4; ++q) {
    int ky = kg + 4 * q;
    __sincosf(-TWO_PI_128 * 4.0f * (float)ky, &s4t[q], &c4t[q]);
    w4r[q] = 1.f; w4i[q] = 0.f;
    #pragma unroll
    for (int p = 0; p < 4; ++p) { s4r[q][p] = 0.f; s4i[q][p] = 0.f; }
  }
  for (int m = 0; m < 32; ++m) {
    float hv[4];
    #pragma unroll
    for (int p = 0; p < 4; ++p) hv[p] = sh[(4 * m + p) * 64 + c];
    #pragma unroll
    for (int q = 0; q < 4; ++q) {
      #pragma unroll
      for (int p = 0; p < 4; ++p) {
        s4r[q][p] = fmaf(hv[p], w4r[q], s4r[q][p]);
        s4i[q][p] = fmaf(hv[p], w4i[q], s4i[q][p]);
      }
      float nw = w4r[q] * c4t[q] - w4i[q] * s4t[q];
      w4i[q] = fmaf(w4i[q], c4t[q], w4r[q] * s4t[q]);
      w4r[q] = nw;
    }
  }
  #pragma unroll
  for (int q = 0; q < 4; ++q) {
    int ky = kg + 4 * q;
    float s1, c1;
    __sincosf(-TWO_PI_128 * (float)ky, &s1, &c1);
    float sr = s4r[q][0], si = s4i[q][0];
    float wr_ = c1, wi_ = s1;
    #pragma unroll
    for (int p = 1; p < 4; ++p) {
      sr = fmaf(s4r[q][p], wr_, sr); sr = fmaf(-s4i[q][p], wi_, sr);
      si = fmaf(s4r[q][p], wi_, si); si = fmaf(s4i[q][p], wr_, si);
      float nw = wr_ * c1 - wi_ * s1;
      wi_ = fmaf(wi_, c1, wr_ * s1);
      wr_ = nw;
    }
    A1[((size_t)bx * 16 + ky) * 64 + c] = make_float2(sr, si);
  }
}

// Forward truncated DFT along x (H axis): rows (b*16+kx), cols (ky*64+c)
__global__ __launch_bounds__(256) void k_dft_x(const float2* __restrict__ A1,
    float* __restrict__ Ar, float* __restrict__ Ai) {
  __shared__ float2 sh[128 * 32];
  int b = blockIdx.x, ky = blockIdx.y, ch = blockIdx.z;
  int c0 = ch * 32;
  for (int i = threadIdx.x; i < 2048; i += 256) {
    int xx = i >> 4, u = (i & 15) * 2;
    *(float4*)&sh[xx * 32 + u] =
        *(const float4*)&A1[(((size_t)b * 128 + xx) * 16 + ky) * 64 + c0 + u];
  }
  __syncthreads();
  int cl = threadIdx.x & 31, kxg = threadIdx.x >> 5;
  float cs[2], sn[2], wr_[2], wi_[2], sr[2], si[2];
  #pragma unroll
  for (int q = 0; q < 2; ++q) {
    int kx = kxg + 8 * q;
    __sincosf(-TWO_PI_128 * (float)kx, &sn[q], &cs[q]);
    wr_[q] = 1.f; wi_[q] = 0.f; sr[q] = 0.f; si[q] = 0.f;
  }
  for (int xx = 0; xx < 128; ++xx) {
    float2 v = sh[xx * 32 + cl];
    #pragma unroll
    for (int q = 0; q < 2; ++q) {
      sr[q] = fmaf(v.x, wr_[q], sr[q]); sr[q] = fmaf(-v.y, wi_[q], sr[q]);
      si[q] = fmaf(v.x, wi_[q], si[q]); si[q] = fmaf(v.y, wr_[q], si[q]);
      float nw = wr_[q] * cs[q] - wi_[q] * sn[q];
      wi_[q] = fmaf(wi_[q], cs[q], wr_[q] * sn[q]);
      wr_[q] = nw;
    }
  }
  #pragma unroll
  for (int q = 0; q < 2; ++q) {
    int kx = kxg + 8 * q;
    int row = b * 16 + kx, col = ky * 64 + c0 + cl;
    Ar[row * 1024 + col] = sr[q];
    Ai[row * 1024 + col] = si[q];
  }
}

#define CMAC(cr, ci, ax, ay, bx, by)                 \
  cr = fmaf(ax, bx, cr); cr = fmaf(-(ay), by, cr);   \
  ci = fmaf(ax, by, ci); ci = fmaf(ay, bx, ci);

// Complex GEMM: C[256][1024] = A[256][1024] * B[1024][1024], K-split 8.
// 64x64 C-tile / 4x4 acc; partials z=0 -> Cp, z=1..7 -> A1 space; k_csum sums.
// Single barrier per K-tile (classic double-buffer); coalesced B reads/stores.
__global__ __launch_bounds__(256) void k_gemm(const float* __restrict__ Ar,
    const float* __restrict__ Ai, const float* __restrict__ Br,
    const float* __restrict__ Bi, float2* __restrict__ Cp,
    float2* __restrict__ Pp) {
  __shared__ float2 As[2][64][34];   // [row][kk] 34816 B
  __shared__ float2 Bs[2][32][66];   // [kk][j]   33792 B
  int t = threadIdx.x;
  int tx = t & 15, ty = t >> 4;
  int col0 = blockIdx.x * 64, row0 = blockIdx.y * 64, kb0 = blockIdx.z * 128;
  int ra = t >> 2, ka8 = (t & 3) * 8;      // A stage: row ra, k ka8..+7
  int rb = t >> 3, jb8 = (t & 7) * 8;      // B stage: k rb, j jb8..+7
  float4 arv0, arv1, aiv0, aiv1, brv0, brv1, biv0, biv1;
  float cr[4][4] = {{0,0,0,0},{0,0,0,0},{0,0,0,0},{0,0,0,0}};
  float ci[4][4] = {{0,0,0,0},{0,0,0,0},{0,0,0,0},{0,0,0,0}};

  auto ldT = [&](int k0) {
    int g = (row0 + ra) * 1024 + k0 + ka8;
    arv0 = *(const float4*)&Ar[g]; arv1 = *(const float4*)&Ar[g + 4];
    aiv0 = *(const float4*)&Ai[g]; aiv1 = *(const float4*)&Ai[g + 4];
    int gb = (k0 + rb) * 1024 + col0 + jb8;
    brv0 = *(const float4*)&Br[gb]; brv1 = *(const float4*)&Br[gb + 4];
    biv0 = *(const float4*)&Bi[gb]; biv1 = *(const float4*)&Bi[gb + 4];
  };
  auto stT = [&](int buf) {
    *(float4*)&As[buf][ra][ka8]     = make_float4(arv0.x, aiv0.x, arv0.y, aiv0.y);
    *(float4*)&As[buf][ra][ka8 + 2] = make_float4(arv0.z, aiv0.z, arv0.w, aiv0.w);
    *(float4*)&As[buf][ra][ka8 + 4] = make_float4(arv1.x, aiv1.x, arv1.y, aiv1.y);
    *(float4*)&As[buf][ra][ka8 + 6] = make_float4(arv1.z, aiv1.z, arv1.w, aiv1.w);
    *(float4*)&Bs[buf][rb][jb8]     = make_float4(brv0.x, biv0.x, brv0.y, biv0.y);
    *(float4*)&Bs[buf][rb][jb8 + 2] = make_float4(brv0.z, biv0.z, brv0.w, biv0.w);
    *(float4*)&Bs[buf][rb][jb8 + 4] = make_float4(brv1.x, biv1.x, brv1.y, biv1.y);
    *(float4*)&Bs[buf][rb][jb8 + 6] = make_float4(brv1.z, biv1.z, brv1.w, biv1.w);
  };

  ldT(kb0); stT(0);
  __syncthreads();
  for (int kt = 0; kt < 4; ++kt) {
    if (kt < 3) ldT(kb0 + (kt + 1) * 32);   // overlap next-tile loads w/ compute
    int cur = kt & 1;
    #pragma unroll 4
    for (int kk2 = 0; kk2 < 16; ++kk2) {
      float4 av[4];
      #pragma unroll
      for (int rr = 0; rr < 4; ++rr)
        av[rr] = *(const float4*)&As[cur][ty * 4 + rr][kk2 * 2];
      float2 b0[4], b1[4];
      #pragma unroll
      for (int jj = 0; jj < 4; ++jj) b0[jj] = Bs[cur][kk2 * 2][tx + jj * 16];
      #pragma unroll
      for (int jj = 0; jj < 4; ++jj) b1[jj] = Bs[cur][kk2 * 2 + 1][tx + jj * 16];
      #pragma unroll
      for (int rr = 0; rr < 4; ++rr) {
        #pragma unroll
        for (int jj = 0; jj < 4; ++jj) {
          CMAC(cr[rr][jj], ci[rr][jj], av[rr].x, av[rr].y, b0[jj].x, b0[jj].y)
          CMAC(cr[rr][jj], ci[rr][jj], av[rr].z, av[rr].w, b1[jj].x, b1[jj].y)
        }
      }
    }
    if (kt < 3) stT(cur ^ 1);   // safe w/o pre-barrier: cur^1 not read this iter
    __syncthreads();            // stT visible before next iter reads cur^1
  }
  float2* Co = (blockIdx.z == 0) ? Cp : Pp + (size_t)(blockIdx.z - 1) * 262144;
  #pragma unroll
  for (int rr = 0; rr < 4; ++rr) {
    int r = row0 + ty * 4 + rr;
    #pragma unroll
    for (int jj = 0; jj < 4; ++jj) {
      int j = col0 + tx + jj * 16;
      Co[(size_t)r * 1024 + j] = make_float2(cr[rr][jj], ci[rr][jj]);
    }
  }
}

// Reduce the 7 A1-space partials into Cp. 131072 float4 = grid 512.
__global__ __launch_bounds__(256) void k_csum(float2* __restrict__ Cp,
                                              const float2* __restrict__ Pp) {
  int i = blockIdx.x * 256 + threadIdx.x;
  float4* c0 = (float4*)Cp;
  float4 s = c0[i];
  #pragma unroll
  for (int z = 0; z < 7; ++z) {
    float4 v = ((const float4*)(Pp + (size_t)z * 262144))[i];
    s.x += v.x; s.y += v.y; s.z += v.z; s.w += v.w;
  }
  c0[i] = s;
}

// Inverse DFT along the W-frequency axis m -> y (Cp pre-summed by k_csum).
// T layout: [b][y][kx][c]
__global__ __launch_bounds__(256) void k_ifft_y(const float2* __restrict__ Cp,
                                                float2* __restrict__ T) {
  __shared__ float2 Cl[1024];
  int b = blockIdx.x >> 4, kx = blockIdx.x & 15;
  int row = b * 16 + kx;
  for (int i = threadIdx.x; i < 512; i += 256)
    *(float4*)&Cl[i * 2] = *(const float4*)&Cp[(size_t)row * 1024 + i * 2];
  __syncthreads();
  int c = threadIdx.x & 63, yg = threadIdx.x >> 6;
  for (int y = yg; y < 128; y += 4) {
    float snv, csv;
    __sincosf(TWO_PI_128 * (float)y, &snv, &csv);
    float wr_ = 1.f, wi_ = 0.f, sr = 0.f, si = 0.f;
    #pragma unroll
    for (int ky = 0; ky < 16; ++ky) {
      float2 v = Cl[ky * 64 + c];
      sr = fmaf(v.x, wr_, sr); sr = fmaf(-v.y, wi_, sr);
      si = fmaf(v.x, wi_, si); si = fmaf(v.y, wr_, si);
      float nw = wr_ * csv - wi_ * snv;
      wi_ = fmaf(wi_, csv, wr_ * snv);
      wr_ = nw;
    }
    T[(((size_t)b * 128 + y) * 16 + kx) * 64 + c] = make_float2(sr, si);
  }
}

// Fused: inverse DFT along kx -> x (real part) + pointwise h@ww + wb + gelu.
// Block (b,y): reads/writes exactly the h elements at fixed (b,y).
// v7 (960-validated): T row staged in LDS; x2 hv loads straight unroll-1;
// (256,4). NOTE: v8's dbuf + (256,6) variant caused 6.7x HBM write
// amplification (WRITE 64->430 MB): the stride-8 per-float stores rely on
// L2 write-combining, which broke under the higher cache pressure. Keep
// this kernel's occupancy/load-depth AS IS unless the epilogue is made
// float4-coalesced first.
__global__ __launch_bounds__(256, 4) void k_layer_out(const float* hin,
    const float2* __restrict__ T, const float* __restrict__ ww,
    const float* __restrict__ wb, float* hout) {
  __shared__ alignas(16) float wwT[64 * 68];
  __shared__ alignas(16) float2 Tl[1024];
  int b = blockIdx.x >> 7, y = blockIdx.x & 127;
  for (int i = threadIdx.x; i < 1024; i += 256) {
    int k = i >> 4, c4 = (i & 15) << 2;
    float4 v = *(const float4*)&ww[k * 64 + c4];
    wwT[(c4 + 0) * 68 + k] = v.x;
    wwT[(c4 + 1) * 68 + k] = v.y;
    wwT[(c4 + 2) * 68 + k] = v.z;
    wwT[(c4 + 3) * 68 + k] = v.w;
  }
  const float2* Tp = T + ((size_t)b * 128 + y) * 1024;
  for (int i = threadIdx.x; i < 512; i += 256)
    *(float4*)&Tl[i * 2] = *(const float4*)&Tp[i * 2];
  __syncthreads();
  int ct = threadIdx.x & 7, xg = threadIdx.x >> 3;  // c = ct+8cc, x = xg+32j
  float acc[4][8];
  #pragma unroll
  for (int cc = 0; cc < 8; ++cc) {
    float bv = wb[ct + 8 * cc];
    #pragma unroll
    for (int j = 0; j < 4; ++j) acc[j][cc] = bv;
  }
  // x1: real part of sum_kx T[kx][c] * e^{+2pi i kx x/128}
  #pragma unroll
  for (int kx = 0; kx < 16; ++kx) {
    float tr[8], ti[8];
    #pragma unroll
    for (int cc = 0; cc < 8; ++cc) {
      float2 v = Tl[kx * 64 + ct + 8 * cc];
      tr[cc] = v.x; ti[cc] = v.y;
    }
    float s0v, c0v;
    __sincosf(TWO_PI_128 * (float)(kx * xg), &s0v, &c0v);
    float wr_ = c0v, wi_ = s0v;
    #pragma unroll
    for (int j = 0; j < 4; ++j) {
      #pragma unroll
      for (int cc = 0; cc < 8; ++cc) {
        acc[j][cc] = fmaf(tr[cc], wr_, acc[j][cc]);
        acc[j][cc] = fmaf(-ti[cc], wi_, acc[j][cc]);
      }
      // rotate (wr,wi) by i^kx -- kx is unroll-constant, folds at compile time
      float owr = wr_, owi = wi_;
      if ((kx & 3) == 1)      { wr_ = -owi; wi_ =  owr; }
      else if ((kx & 3) == 2) { wr_ = -owr; wi_ = -owi; }
      else if ((kx & 3) == 3) { wr_ =  owi; wi_ = -owr; }
    }
  }
  // x2: h @ ww, h read directly from global (rows x = xg+32j at fixed y)
  const float* hp = hin + (((size_t)b * 128 + xg) * 128 + y) * 64;
  #pragma unroll 1
  for (int kq = 0; kq < 64; kq += 4) {
    float4 wv[8];
    #pragma unroll
    for (int cc = 0; cc < 8; ++cc)
      wv[cc] = *(const float4*)&wwT[(ct + 8 * cc) * 68 + kq];
    #pragma unroll
    for (int j = 0; j < 4; ++j) {
      float4 hv = *(const float4*)&hp[(size_t)j * 262144 + kq];  // 32*128*64
      #pragma unroll
      for (int cc = 0; cc < 8; ++cc) {
        acc[j][cc] = fmaf(hv.x, wv[cc].x, acc[j][cc]);
        acc[j][cc] = fmaf(hv.y, wv[cc].y, acc[j][cc]);
        acc[j][cc] = fmaf(hv.z, wv[cc].z, acc[j][cc]);
        acc[j][cc] = fmaf(hv.w, wv[cc].w, acc[j][cc]);
      }
    }
  }
  __syncthreads();   // all hin reads drained (barrier waits vmcnt) before stores
  #pragma unroll
  for (int j = 0; j < 4; ++j) {
    int xx = xg + 32 * j;
    size_t base = (((size_t)b * 128 + xx) * 128 + y) * 64 + ct;
    #pragma unroll
    for (int cc = 0; cc < 8; ++cc)
      hout[base + 8 * cc] = gelu_f(acc[j][cc]);
  }
}

// Fused fc1 + gelu + fc2.  (round-2 structure; byte-identical anchor kernel --
// also the cross-round clock-noise gauge: judge by dur*VALUBusy products.)
__global__ __launch_bounds__(256) void k_final(const float* __restrict__ h,
    const float* __restrict__ w1, const float* __restrict__ b1,
    const float* __restrict__ w2, const float* __restrict__ b2,
    float* __restrict__ out) {
  __shared__ alignas(16) float w1T[128 * 68];   // w1T[j][k]
  __shared__ alignas(16) float hl[128 * 68];    // hl[r][k]
  __shared__ float b1s[128];
  __shared__ float w2s[128];
  for (int i = threadIdx.x; i < 8192; i += 256) {
    int k = i >> 7, j = i & 127;
    w1T[j * 68 + k] = w1[i];
  }
  if (threadIdx.x < 128) {
    b1s[threadIdx.x] = b1[threadIdx.x];
    w2s[threadIdx.x] = w2[threadIdx.x];
  }
  int r0 = blockIdx.x * 128;
  for (int i = threadIdx.x; i < 2048; i += 256) {
    int r = i >> 4, kq = (i & 15) * 4;          // coalesced float4 row loads
    float4 v = *(const float4*)&h[(size_t)(r0 + r) * 64 + kq];
    *(float4*)&hl[r * 68 + kq] = v;
  }
  __syncthreads();
  int jt = threadIdx.x & 15, rg = threadIdx.x >> 4;  // j = jt+16*cc, r = rg+16*ii
  float acc[8][8];   // [ii][cc]
  #pragma unroll
  for (int cc = 0; cc < 8; ++cc) {
    float bv = b1s[jt + 16 * cc];
    #pragma unroll
    for (int ii = 0; ii < 8; ++ii) acc[ii][cc] = bv;
  }
  #pragma unroll 1
  for (int kq = 0; kq < 64; kq += 4) {
    float4 hv[8];
    #pragma unroll
    for (int ii = 0; ii < 8; ++ii)
      hv[ii] = *(const float4*)&hl[(rg + 16 * ii) * 68 + kq];
    #pragma unroll
    for (int cc = 0; cc < 8; ++cc) {
      float4 wv = *(const float4*)&w1T[(jt + 16 * cc) * 68 + kq];
      #pragma unroll
      for (int ii = 0; ii < 8; ++ii) {
        acc[ii][cc] = fmaf(hv[ii].x, wv.x, acc[ii][cc]);
        acc[ii][cc] = fmaf(hv[ii].y, wv.y, acc[ii][cc]);
        acc[ii][cc] = fmaf(hv[ii].z, wv.z, acc[ii][cc]);
        acc[ii][cc] = fmaf(hv[ii].w, wv.w, acc[ii][cc]);
      }
    }
  }
  float b2v = b2[0];
  #pragma unroll
  for (int ii = 0; ii < 8; ++ii) {
    float part = 0.f;
    #pragma unroll
    for (int cc = 0; cc < 8; ++cc)
      part = fmaf(gelu_f(acc[ii][cc]), w2s[jt + 16 * cc], part);
    part += __shfl_xor(part, 1, 64);
    part += __shfl_xor(part, 2, 64);
    part += __shfl_xor(part, 4, 64);
    part += __shfl_xor(part, 8, 64);
    if (jt == 0) out[r0 + rg + 16 * ii] = part + b2v;
  }
}

extern "C" void kernel_launch(void* const* d_in, const int* in_sizes, int n_in,
                              void* d_out, int out_size, void* d_ws, size_t ws_size,
                              hipStream_t stream) {
  (void)in_sizes; (void)n_in; (void)out_size; (void)ws_size;
  const float* x      = (const float*)d_in[0];
  const float* fcin_w = (const float*)d_in[1];
  const float* fcin_b = (const float*)d_in[2];
  const float* wr     = (const float*)d_in[3];
  const float* wi     = (const float*)d_in[4];
  const float* ww     = (const float*)d_in[5];
  const float* wb     = (const float*)d_in[6];
  const float* fc1_w  = (const float*)d_in[7];
  const float* fc1_b  = (const float*)d_in[8];
  const float* fc2_w  = (const float*)d_in[9];
  const float* fc2_b  = (const float*)d_in[10];
  float* out = (float*)d_out;

  // workspace layout (floats): 96.5 MB total (within the validated 98.6 MB).
  // A1's 16 MB doubles as the GEMM partial buffer (z=1..7, 14 MB): A1 is dead
  // between k_dft_x (last read) and k_ifft_y (T write), and k_csum drains the
  // partials into Cp before k_ifft_y runs. Stream order serializes all of it.
  float*  hA = (float*)d_ws;              // 16,777,216
  float2* A1 = (float2*)(hA + 16777216);  // 2,097,152 float2 (A1 / T / partials)
  float*  Ar = (float*)(A1 + 2097152);    // 262,144
  float*  Ai = Ar + 262144;               // 262,144
  float*  Br = Ai + 262144;               // 1,048,576
  float*  Bi = Br + 1048576;              // 1,048,576
  float2* Cp = (float2*)(Bi + 1048576);   // 262,144 float2 (z=0 partial / sum)

  k_fc_in<<<16384, 256, 0, stream>>>(x, fcin_w, fcin_b, hA);
  for (int l = 0; l < 4; ++l) {
    k_prep<<<4096, 256, 0, stream>>>(wr + (size_t)l * 8388608,
                                     wi + (size_t)l * 8388608, Br, Bi);
    k_dft_y<<<2048, 256, 0, stream>>>(hA, A1);
    k_dft_x<<<dim3(16, 16, 2), 256, 0, stream>>>(A1, Ar, Ai);
    k_gemm<<<dim3(16, 4, 8), 256, 0, stream>>>(Ar, Ai, Br, Bi, Cp, A1);
    k_csum<<<512, 256, 0, stream>>>(Cp, A1);
    k_ifft_y<<<256, 256, 0, stream>>>(Cp, A1);     // A1 now holds T
    k_layer_out<<<2048, 256, 0, stream>>>(hA, A1, ww + (size_t)l * 4096,
                                          wb + (size_t)l * 64, hA);
  }
  k_final<<<2048, 256, 0, stream>>>(hA, fc1_w, fc1_b, fc2_w, fc2_b, out);
}

// Round 12
// 942.320 us; speedup vs baseline: 1.5253x; 1.0278x over previous
//
#include <hip/hip_runtime.h>
#include <math.h>

// Sizes: B=16, H=128, W=128, C=64, MODES=16, SCHMIDT=8, N_LAYERS=4
// h buffer: 16*128*128*64 = 16,777,216 floats (67 MB), updated in place per layer.

#define TWO_PI_128 0.049087385212340517f   // 2*pi/128

typedef __attribute__((ext_vector_type(8))) short bf16x8;
typedef __attribute__((ext_vector_type(4))) float f32x4;

// gelu(v) = v * (1 - 1/(e^{2u} + 1)), u = 0.79788456 v (1 + 0.044715 v^2)
__device__ __forceinline__ float gelu_f(float v) {
  float ex = 1.5957691216057308f * v * fmaf(0.044715f, v * v, 1.0f);  // 2u
  float e = __expf(fminf(ex, 30.0f));      // clamp: avoid inf -> NaN in rcp
  float r = __builtin_amdgcn_rcpf(e + 1.0f);
  return fmaf(-v, r, v);
}

// round-to-nearest-even bf16 (bit ops only; values are tame, no NaN handling)
__device__ __forceinline__ ushort bf16_rne(float v, float& back) {
  uint u = __float_as_uint(v);
  uint r = (u + 0x7FFFu + ((u >> 16) & 1u)) >> 16;
  back = __uint_as_float(r << 16);
  return (ushort)r;
}

// h[pix][c4..c4+3] = x[pix][:3] @ w + b   (float4 over c)
__global__ __launch_bounds__(256) void k_fc_in(const float* __restrict__ x,
    const float* __restrict__ w, const float* __restrict__ b,
    float* __restrict__ h) {
  int t = blockIdx.x * 256 + threadIdx.x;   // over NPIX*16
  int pix = t >> 4, c4 = (t & 15) << 2;
  float x0 = x[pix * 3], x1 = x[pix * 3 + 1], x2 = x[pix * 3 + 2];
  float4 acc = *(const float4*)&b[c4];
  float4 w0 = *(const float4*)&w[c4];
  float4 w1 = *(const float4*)&w[64 + c4];
  float4 w2 = *(const float4*)&w[128 + c4];
  acc.x = fmaf(x2, w2.x, fmaf(x1, w1.x, fmaf(x0, w0.x, acc.x)));
  acc.y = fmaf(x2, w2.y, fmaf(x1, w1.y, fmaf(x0, w0.y, acc.y)));
  acc.z = fmaf(x2, w2.z, fmaf(x1, w1.z, fmaf(x0, w0.z, acc.z)));
  acc.w = fmaf(x2, w2.w, fmaf(x1, w1.w, fmaf(x0, w0.w, acc.w)));
  *(float4*)&h[(size_t)pix * 64 + c4] = acc;
}

// Fold Schmidt sum + 1/sqrt(8) + 1/(128*128) into complex weight,
// laid out for GEMM: Br/Bi[(n*64+c)*1024 + (m*64+o)]
__global__ __launch_bounds__(256) void k_prep(const float* __restrict__ wr,
    const float* __restrict__ wi, float* __restrict__ Br, float* __restrict__ Bi) {
  int t = blockIdx.x * 256 + threadIdx.x;     // linear over (m,n,c,o), o innermost
  int o = t & 63, c = (t >> 6) & 63, n = (t >> 12) & 15, m = t >> 16;
  const float4* pr = (const float4*)(wr) + (size_t)t * 2;
  float4 a = pr[0], d = pr[1];
  float sr = ((a.x + a.y) + (a.z + a.w)) + ((d.x + d.y) + (d.z + d.w));
  const float4* pi = (const float4*)(wi) + (size_t)t * 2;
  a = pi[0]; d = pi[1];
  float si = ((a.x + a.y) + (a.z + a.w)) + ((d.x + d.y) + (d.z + d.w));
  const float scale = 0.35355339059327373f / 16384.0f;  // 1/(sqrt(8)*128*128)
  int k = n * 64 + c, j = m * 64 + o;
  Br[k * 1024 + j] = sr * scale;
  Bi[k * 1024 + j] = si * scale;
}

// Forward truncated DFT along y (W axis): A1[b][x][ky][c], ky<16
// radix-4 sub-accumulation: one twiddle recurrence per 4 samples.
__global__ __launch_bounds__(256) void k_dft_y(const float* __restrict__ h,
                                               float2* __restrict__ A1) {
  __shared__ float sh[128 * 64];
  int bx = blockIdx.x;                        // b*128 + x
  const float* src = h + (size_t)bx * 8192;
  for (int i = threadIdx.x; i < 2048; i += 256)
    *(float4*)&sh[i * 4] = *(const float4*)&src[i * 4];
  __syncthreads();
  int c = threadIdx.x & 63, kg = threadIdx.x >> 6;
  float s4r[4][4], s4i[4][4];                 // [q][p]
  float w4r[4], w4i[4], c4t[4], s4t[4];
  #pragma unroll
  for (int q = 0; q < 4; ++q) {
    int ky = kg + 4 * q;
    __sincosf(-TWO_PI_128 * 4.0f * (float)ky, &s4t[q], &c4t[q]);
    w4r[q] = 1.f; w4i[q] = 0.f;
    #pragma unroll
    for (int p = 0; p < 4; ++p) { s4r[q][p] = 0.f; s4i[q][p] = 0.f; }
  }
  for (int m = 0; m < 32; ++m) {
    float hv[4];
    #pragma unroll
    for (int p = 0; p < 4; ++p) hv[p] = sh[(4 * m + p) * 64 + c];
    #pragma unroll
    for (int q = 0; q < 4; ++q) {
      #pragma unroll
      for (int p = 0; p < 4; ++p) {
        s4r[q][p] = fmaf(hv[p], w4r[q], s4r[q][p]);
        s4i[q][p] = fmaf(hv[p], w4i[q], s4i[q][p]);
      }
      float nw = w4r[q] * c4t[q] - w4i[q] * s4t[q];
      w4i[q] = fmaf(w4i[q], c4t[q], w4r[q] * s4t[q]);
      w4r[q] = nw;
    }
  }
  #pragma unroll
  for (int q = 0; q < 4; ++q) {
    int ky = kg + 4 * q;
    float s1, c1;
    __sincosf(-TWO_PI_128 * (float)ky, &s1, &c1);
    float sr = s4r[q][0], si = s4i[q][0];
    float wr_ = c1, wi_ = s1;
    #pragma unroll
    for (int p = 1; p < 4; ++p) {
      sr = fmaf(s4r[q][p], wr_, sr); sr = fmaf(-s4i[q][p], wi_, sr);
      si = fmaf(s4r[q][p], wi_, si); si = fmaf(s4i[q][p], wr_, si);
      float nw = wr_ * c1 - wi_ * s1;
      wi_ = fmaf(wi_, c1, wr_ * s1);
      wr_ = nw;
    }
    A1[((size_t)bx * 16 + ky) * 64 + c] = make_float2(sr, si);
  }
}

// Forward truncated DFT along x (H axis): rows (b*16+kx), cols (ky*64+c)
__global__ __launch_bounds__(256) void k_dft_x(const float2* __restrict__ A1,
    float* __restrict__ Ar, float* __restrict__ Ai) {
  __shared__ float2 sh[128 * 32];
  int b = blockIdx.x, ky = blockIdx.y, ch = blockIdx.z;
  int c0 = ch * 32;
  for (int i = threadIdx.x; i < 2048; i += 256) {
    int xx = i >> 4, u = (i & 15) * 2;
    *(float4*)&sh[xx * 32 + u] =
        *(const float4*)&A1[(((size_t)b * 128 + xx) * 16 + ky) * 64 + c0 + u];
  }
  __syncthreads();
  int cl = threadIdx.x & 31, kxg = threadIdx.x >> 5;
  float cs[2], sn[2], wr_[2], wi_[2], sr[2], si[2];
  #pragma unroll
  for (int q = 0; q < 2; ++q) {
    int kx = kxg + 8 * q;
    __sincosf(-TWO_PI_128 * (float)kx, &sn[q], &cs[q]);
    wr_[q] = 1.f; wi_[q] = 0.f; sr[q] = 0.f; si[q] = 0.f;
  }
  for (int xx = 0; xx < 128; ++xx) {
    float2 v = sh[xx * 32 + cl];
    #pragma unroll
    for (int q = 0; q < 2; ++q) {
      sr[q] = fmaf(v.x, wr_[q], sr[q]); sr[q] = fmaf(-v.y, wi_[q], sr[q]);
      si[q] = fmaf(v.x, wi_[q], si[q]); si[q] = fmaf(v.y, wr_[q], si[q]);
      float nw = wr_[q] * cs[q] - wi_[q] * sn[q];
      wi_[q] = fmaf(wi_[q], cs[q], wr_[q] * sn[q]);
      wr_[q] = nw;
    }
  }
  #pragma unroll
  for (int q = 0; q < 2; ++q) {
    int kx = kxg + 8 * q;
    int row = b * 16 + kx, col = ky * 64 + c0 + cl;
    Ar[row * 1024 + col] = sr[q];
    Ai[row * 1024 + col] = si[q];
  }
}

// Split A (fp32 [256][1024]) into bf16 hi/lo planes, layout [row][k] bf16.
// A-fragment reads (8 consecutive k per lane) are 16B-contiguous in this
// layout, so no transpose needed. Planes: 0=ArH 1=ArL 2=AiH 3=AiL.
__global__ __launch_bounds__(256) void k_asplit(const float* __restrict__ Ar,
    const float* __restrict__ Ai, ushort* __restrict__ Ap) {
  int g = blockIdx.x * 256 + threadIdx.x;   // 32768: (row, kgroup8)
  size_t off = (size_t)g * 8;
  float4 r0 = *(const float4*)&Ar[off], r1 = *(const float4*)&Ar[off + 4];
  float4 i0 = *(const float4*)&Ai[off], i1 = *(const float4*)&Ai[off + 4];
  float vr[8] = {r0.x, r0.y, r0.z, r0.w, r1.x, r1.y, r1.z, r1.w};
  float vi[8] = {i0.x, i0.y, i0.z, i0.w, i1.x, i1.y, i1.z, i1.w};
  ushort hr[8], lr[8], hi_[8], li[8];
  #pragma unroll
  for (int j = 0; j < 8; ++j) {
    float back, d;
    hr[j] = bf16_rne(vr[j], back);
    lr[j] = bf16_rne(vr[j] - back, d);
    hi_[j] = bf16_rne(vi[j], back);
    li[j] = bf16_rne(vi[j] - back, d);
  }
  auto pack = [](const ushort* s) {
    return make_uint4((uint)s[0] | ((uint)s[1] << 16), (uint)s[2] | ((uint)s[3] << 16),
                      (uint)s[4] | ((uint)s[5] << 16), (uint)s[6] | ((uint)s[7] << 16));
  };
  *(uint4*)(Ap + 0 * 262144 + off) = pack(hr);
  *(uint4*)(Ap + 1 * 262144 + off) = pack(lr);
  *(uint4*)(Ap + 2 * 262144 + off) = pack(hi_);
  *(uint4*)(Ap + 3 * 262144 + off) = pack(li);
}

// Split+transpose B (fp32 [1024 k][1024 j]) into bf16 hi/lo planes in
// MFMA-fragment-major layout: Bf[p][((nt*32+ks)*64 + lane)*8 + j] holds
// B[k = ks*32 + (lane>>4)*8 + j][col = nt*16 + (lane&15)].
// Reads are k-strided (L2-resident, 16-col segments per 16-lane group);
// writes are perfectly coalesced 16B/lane.
__global__ __launch_bounds__(256) void k_bsplit(const float* __restrict__ Br,
    const float* __restrict__ Bi, ushort* __restrict__ Bf) {
  int t = blockIdx.x * 256 + threadIdx.x;   // 131072: (nt, ks, lane)
  int l = t & 63, ks = (t >> 6) & 31, nt = t >> 11;
  int col = nt * 16 + (l & 15);
  int kb = ks * 32 + (l >> 4) * 8;
  ushort hr[8], lr[8], hi_[8], li[8];
  #pragma unroll
  for (int j = 0; j < 8; ++j) {
    float vr = Br[(size_t)(kb + j) * 1024 + col];
    float vi = Bi[(size_t)(kb + j) * 1024 + col];
    float back, d;
    hr[j] = bf16_rne(vr, back);
    lr[j] = bf16_rne(vr - back, d);
    hi_[j] = bf16_rne(vi, back);
    li[j] = bf16_rne(vi - back, d);
  }
  auto pack = [](const ushort* s) {
    return make_uint4((uint)s[0] | ((uint)s[1] << 16), (uint)s[2] | ((uint)s[3] << 16),
                      (uint)s[4] | ((uint)s[5] << 16), (uint)s[6] | ((uint)s[7] << 16));
  };
  size_t off = (size_t)t * 8;
  *(uint4*)(Bf + 0 * 1048576 + off) = pack(hr);
  *(uint4*)(Bf + 1 * 1048576 + off) = pack(lr);
  *(uint4*)(Bf + 2 * 1048576 + off) = pack(hi_);
  *(uint4*)(Bf + 3 * 1048576 + off) = pack(li);
}

// Complex GEMM via split-bf16 MFMA. C[256][1024] = A x B, K=1024, K-split 2.
// One wave = one 16x16 out-tile (+K-half). 12 mfma_f32_16x16x32_bf16 per
// K-step into 4 accumulators (3-term split products: HH+HL+LH; dropped LL
// ~2^-18 relative). Epilogue: Cr = rr - ii, Ci = ri + ir. No LDS/barriers.
// Layouts (guide-verified C/D, standard A/B): A row=lane&15, k=(lane>>4)*8+j;
// B frag pre-transposed by k_bsplit; D col=lane&15, row=(lane>>4)*4+q.
__global__ __launch_bounds__(256) void k_gemm_mfma(const ushort* __restrict__ Ap,
    const ushort* __restrict__ Bf, float2* __restrict__ Cp,
    float2* __restrict__ Pz1) {
  int wid = threadIdx.x >> 6, l = threadIdx.x & 63;
  int bid = blockIdx.x;                 // 512
  int z = bid & 1;
  int tile = (bid >> 1) * 4 + wid;      // 0..1023
  int tr = tile & 15, tc = tile >> 4;   // 16 row-tiles x 64 col-tiles
  int r0 = tr * 16;
  int lr = l & 15, lk = l >> 4;
  size_t aoff = (size_t)(r0 + lr) * 1024 + z * 512 + lk * 8;   // shorts
  size_t boff = (((size_t)tc * 32 + z * 16) * 64 + l) * 8;
  f32x4 rr = {0,0,0,0}, ii = {0,0,0,0}, ri = {0,0,0,0}, ir = {0,0,0,0};
  #pragma unroll 4
  for (int ks = 0; ks < 16; ++ks) {
    bf16x8 arH = *(const bf16x8*)(Ap + 0 * 262144 + aoff);
    bf16x8 arL = *(const bf16x8*)(Ap + 1 * 262144 + aoff);
    bf16x8 aiH = *(const bf16x8*)(Ap + 2 * 262144 + aoff);
    bf16x8 aiL = *(const bf16x8*)(Ap + 3 * 262144 + aoff);
    bf16x8 brH = *(const bf16x8*)(Bf + 0 * 1048576 + boff);
    bf16x8 brL = *(const bf16x8*)(Bf + 1 * 1048576 + boff);
    bf16x8 biH = *(const bf16x8*)(Bf + 2 * 1048576 + boff);
    bf16x8 biL = *(const bf16x8*)(Bf + 3 * 1048576 + boff);
    rr = __builtin_amdgcn_mfma_f32_16x16x32_bf16(arH, brH, rr, 0, 0, 0);
    rr = __builtin_amdgcn_mfma_f32_16x16x32_bf16(arH, brL, rr, 0, 0, 0);
    rr = __builtin_amdgcn_mfma_f32_16x16x32_bf16(arL, brH, rr, 0, 0, 0);
    ii = __builtin_amdgcn_mfma_f32_16x16x32_bf16(aiH, biH, ii, 0, 0, 0);
    ii = __builtin_amdgcn_mfma_f32_16x16x32_bf16(aiH, biL, ii, 0, 0, 0);
    ii = __builtin_amdgcn_mfma_f32_16x16x32_bf16(aiL, biH, ii, 0, 0, 0);
    ri = __builtin_amdgcn_mfma_f32_16x16x32_bf16(arH, biH, ri, 0, 0, 0);
    ri = __builtin_amdgcn_mfma_f32_16x16x32_bf16(arH, biL, ri, 0, 0, 0);
    ri = __builtin_amdgcn_mfma_f32_16x16x32_bf16(arL, biH, ri, 0, 0, 0);
    ir = __builtin_amdgcn_mfma_f32_16x16x32_bf16(aiH, brH, ir, 0, 0, 0);
    ir = __builtin_amdgcn_mfma_f32_16x16x32_bf16(aiH, brL, ir, 0, 0, 0);
    ir = __builtin_amdgcn_mfma_f32_16x16x32_bf16(aiL, brH, ir, 0, 0, 0);
    aoff += 32;
    boff += 512;
  }
  float2* Co = z ? Pz1 : Cp;
  int col = tc * 16 + lr;
  #pragma unroll
  for (int q = 0; q < 4; ++q) {
    int row = r0 + lk * 4 + q;
    Co[(size_t)row * 1024 + col] = make_float2(rr[q] - ii[q], ri[q] + ir[q]);
  }
}

// Inverse DFT along the W-frequency axis m -> y; sums the 2 K-split partials.
// T layout: [b][y][kx][c]
__global__ __launch_bounds__(256) void k_ifft_y(const float2* __restrict__ Cp,
    const float2* __restrict__ P1, float2* __restrict__ T) {
  __shared__ float2 Cl[1024];
  int b = blockIdx.x >> 4, kx = blockIdx.x & 15;
  int row = b * 16 + kx;
  for (int i = threadIdx.x; i < 512; i += 256) {
    float4 u = *(const float4*)&Cp[(size_t)row * 1024 + i * 2];
    float4 v = *(const float4*)&P1[(size_t)row * 1024 + i * 2];
    *(float4*)&Cl[i * 2] = make_float4(u.x + v.x, u.y + v.y, u.z + v.z, u.w + v.w);
  }
  __syncthreads();
  int c = threadIdx.x & 63, yg = threadIdx.x >> 6;
  for (int y = yg; y < 128; y += 4) {
    float snv, csv;
    __sincosf(TWO_PI_128 * (float)y, &snv, &csv);
    float wr_ = 1.f, wi_ = 0.f, sr = 0.f, si = 0.f;
    #pragma unroll
    for (int ky = 0; ky < 16; ++ky) {
      float2 v = Cl[ky * 64 + c];
      sr = fmaf(v.x, wr_, sr); sr = fmaf(-v.y, wi_, sr);
      si = fmaf(v.x, wi_, si); si = fmaf(v.y, wr_, si);
      float nw = wr_ * csv - wi_ * snv;
      wi_ = fmaf(wi_, csv, wr_ * snv);
      wr_ = nw;
    }
    T[(((size_t)b * 128 + y) * 16 + kx) * 64 + c] = make_float2(sr, si);
  }
}

// Fused: inverse DFT along kx -> x (real part) + pointwise h@ww + wb + gelu.
// Block (b,y): reads/writes exactly the h elements at fixed (b,y).
// v7 (960-validated): T row staged in LDS; x2 hv loads straight unroll-1;
// (256,4). NOTE: the dbuf + (256,6) variant caused 6.7x HBM write
// amplification (stride-8 stores rely on L2 write-combining, which broke
// under higher cache pressure). Keep occupancy/load-depth AS IS.
__global__ __launch_bounds__(256, 4) void k_layer_out(const float* hin,
    const float2* __restrict__ T, const float* __restrict__ ww,
    const float* __restrict__ wb, float* hout) {
  __shared__ alignas(16) float wwT[64 * 68];
  __shared__ alignas(16) float2 Tl[1024];
  int b = blockIdx.x >> 7, y = blockIdx.x & 127;
  for (int i = threadIdx.x; i < 1024; i += 256) {
    int k = i >> 4, c4 = (i & 15) << 2;
    float4 v = *(const float4*)&ww[k * 64 + c4];
    wwT[(c4 + 0) * 68 + k] = v.x;
    wwT[(c4 + 1) * 68 + k] = v.y;
    wwT[(c4 + 2) * 68 + k] = v.z;
    wwT[(c4 + 3) * 68 + k] = v.w;
  }
  const float2* Tp = T + ((size_t)b * 128 + y) * 1024;
  for (int i = threadIdx.x; i < 512; i += 256)
    *(float4*)&Tl[i * 2] = *(const float4*)&Tp[i * 2];
  __syncthreads();
  int ct = threadIdx.x & 7, xg = threadIdx.x >> 3;  // c = ct+8cc, x = xg+32j
  float acc[4][8];
  #pragma unroll
  for (int cc = 0; cc < 8; ++cc) {
    float bv = wb[ct + 8 * cc];
    #pragma unroll
    for (int j = 0; j < 4; ++j) acc[j][cc] = bv;
  }
  // x1: real part of sum_kx T[kx][c] * e^{+2pi i kx x/128}
  #pragma unroll
  for (int kx = 0; kx < 16; ++kx) {
    float tr[8], ti[8];
    #pragma unroll
    for (int cc = 0; cc < 8; ++cc) {
      float2 v = Tl[kx * 64 + ct + 8 * cc];
      tr[cc] = v.x; ti[cc] = v.y;
    }
    float s0v, c0v;
    __sincosf(TWO_PI_128 * (float)(kx * xg), &s0v, &c0v);
    float wr_ = c0v, wi_ = s0v;
    #pragma unroll
    for (int j = 0; j < 4; ++j) {
      #pragma unroll
      for (int cc = 0; cc < 8; ++cc) {
        acc[j][cc] = fmaf(tr[cc], wr_, acc[j][cc]);
        acc[j][cc] = fmaf(-ti[cc], wi_, acc[j][cc]);
      }
      // rotate (wr,wi) by i^kx -- kx is unroll-constant, folds at compile time
      float owr = wr_, owi = wi_;
      if ((kx & 3) == 1)      { wr_ = -owi; wi_ =  owr; }
      else if ((kx & 3) == 2) { wr_ = -owr; wi_ = -owi; }
      else if ((kx & 3) == 3) { wr_ =  owi; wi_ = -owr; }
    }
  }
  // x2: h @ ww, h read directly from global (rows x = xg+32j at fixed y)
  const float* hp = hin + (((size_t)b * 128 + xg) * 128 + y) * 64;
  #pragma unroll 1
  for (int kq = 0; kq < 64; kq += 4) {
    float4 wv[8];
    #pragma unroll
    for (int cc = 0; cc < 8; ++cc)
      wv[cc] = *(const float4*)&wwT[(ct + 8 * cc) * 68 + kq];
    #pragma unroll
    for (int j = 0; j < 4; ++j) {
      float4 hv = *(const float4*)&hp[(size_t)j * 262144 + kq];  // 32*128*64
      #pragma unroll
      for (int cc = 0; cc < 8; ++cc) {
        acc[j][cc] = fmaf(hv.x, wv[cc].x, acc[j][cc]);
        acc[j][cc] = fmaf(hv.y, wv[cc].y, acc[j][cc]);
        acc[j][cc] = fmaf(hv.z, wv[cc].z, acc[j][cc]);
        acc[j][cc] = fmaf(hv.w, wv[cc].w, acc[j][cc]);
      }
    }
  }
  __syncthreads();   // all hin reads drained (barrier waits vmcnt) before stores
  #pragma unroll
  for (int j = 0; j < 4; ++j) {
    int xx = xg + 32 * j;
    size_t base = (((size_t)b * 128 + xx) * 128 + y) * 64 + ct;
    #pragma unroll
    for (int cc = 0; cc < 8; ++cc)
      hout[base + 8 * cc] = gelu_f(acc[j][cc]);
  }
}

// Fused fc1 + gelu + fc2.  (round-2 structure; byte-identical anchor kernel --
// also the cross-round clock-noise gauge: judge by dur*VALUBusy products.)
__global__ __launch_bounds__(256) void k_final(const float* __restrict__ h,
    const float* __restrict__ w1, const float* __restrict__ b1,
    const float* __restrict__ w2, const float* __restrict__ b2,
    float* __restrict__ out) {
  __shared__ alignas(16) float w1T[128 * 68];   // w1T[j][k]
  __shared__ alignas(16) float hl[128 * 68];    // hl[r][k]
  __shared__ float b1s[128];
  __shared__ float w2s[128];
  for (int i = threadIdx.x; i < 8192; i += 256) {
    int k = i >> 7, j = i & 127;
    w1T[j * 68 + k] = w1[i];
  }
  if (threadIdx.x < 128) {
    b1s[threadIdx.x] = b1[threadIdx.x];
    w2s[threadIdx.x] = w2[threadIdx.x];
  }
  int r0 = blockIdx.x * 128;
  for (int i = threadIdx.x; i < 2048; i += 256) {
    int r = i >> 4, kq = (i & 15) * 4;          // coalesced float4 row loads
    float4 v = *(const float4*)&h[(size_t)(r0 + r) * 64 + kq];
    *(float4*)&hl[r * 68 + kq] = v;
  }
  __syncthreads();
  int jt = threadIdx.x & 15, rg = threadIdx.x >> 4;  // j = jt+16*cc, r = rg+16*ii
  float acc[8][8];   // [ii][cc]
  #pragma unroll
  for (int cc = 0; cc < 8; ++cc) {
    float bv = b1s[jt + 16 * cc];
    #pragma unroll
    for (int ii = 0; ii < 8; ++ii) acc[ii][cc] = bv;
  }
  #pragma unroll 1
  for (int kq = 0; kq < 64; kq += 4) {
    float4 hv[8];
    #pragma unroll
    for (int ii = 0; ii < 8; ++ii)
      hv[ii] = *(const float4*)&hl[(rg + 16 * ii) * 68 + kq];
    #pragma unroll
    for (int cc = 0; cc < 8; ++cc) {
      float4 wv = *(const float4*)&w1T[(jt + 16 * cc) * 68 + kq];
      #pragma unroll
      for (int ii = 0; ii < 8; ++ii) {
        acc[ii][cc] = fmaf(hv[ii].x, wv.x, acc[ii][cc]);
        acc[ii][cc] = fmaf(hv[ii].y, wv.y, acc[ii][cc]);
        acc[ii][cc] = fmaf(hv[ii].z, wv.z, acc[ii][cc]);
        acc[ii][cc] = fmaf(hv[ii].w, wv.w, acc[ii][cc]);
      }
    }
  }
  float b2v = b2[0];
  #pragma unroll
  for (int ii = 0; ii < 8; ++ii) {
    float part = 0.f;
    #pragma unroll
    for (int cc = 0; cc < 8; ++cc)
      part = fmaf(gelu_f(acc[ii][cc]), w2s[jt + 16 * cc], part);
    part += __shfl_xor(part, 1, 64);
    part += __shfl_xor(part, 2, 64);
    part += __shfl_xor(part, 4, 64);
    part += __shfl_xor(part, 8, 64);
    if (jt == 0) out[r0 + rg + 16 * ii] = part + b2v;
  }
}

extern "C" void kernel_launch(void* const* d_in, const int* in_sizes, int n_in,
                              void* d_out, int out_size, void* d_ws, size_t ws_size,
                              hipStream_t stream) {
  (void)in_sizes; (void)n_in; (void)out_size; (void)ws_size;
  const float* x      = (const float*)d_in[0];
  const float* fcin_w = (const float*)d_in[1];
  const float* fcin_b = (const float*)d_in[2];
  const float* wr     = (const float*)d_in[3];
  const float* wi     = (const float*)d_in[4];
  const float* ww     = (const float*)d_in[5];
  const float* wb     = (const float*)d_in[6];
  const float* fc1_w  = (const float*)d_in[7];
  const float* fc1_b  = (const float*)d_in[8];
  const float* fc2_w  = (const float*)d_in[9];
  const float* fc2_b  = (const float*)d_in[10];
  float* out = (float*)d_out;

  // workspace layout (floats): 96.5 MB total (within the validated 98.6 MB).
  // A1's 16 MB region is time-shared: (1) A1 spectral data (dft_y -> dft_x),
  // (2) Bf bf16 planes 8 MB + A bf16 planes 2 MB (bsplit/asplit -> gemm),
  // (3) T output (ifft_y -> layer_out). Ar/Ai (2 MB) are dead after asplit,
  // so the gemm's z=1 partial reuses them. Stream order serializes all of it.
  float*  hA = (float*)d_ws;              // 16,777,216
  float2* A1 = (float2*)(hA + 16777216);  // 2,097,152 float2 (A1 / Bf+Ap / T)
  float*  Ar = (float*)(A1 + 2097152);    // 262,144
  float*  Ai = Ar + 262144;               // 262,144
  float*  Br = Ai + 262144;               // 1,048,576
  float*  Bi = Br + 1048576;              // 1,048,576
  float2* Cp = (float2*)(Bi + 1048576);   // 262,144 float2 (z=0 partial)
  ushort* Bf = (ushort*)A1;               // 4 x 1,048,576 shorts (8 MB)
  ushort* Ap = Bf + 4 * 1048576;          // 4 x 262,144 shorts (2 MB)
  float2* Pz1 = (float2*)Ar;              // 262,144 float2 (z=1 partial)

  k_fc_in<<<16384, 256, 0, stream>>>(x, fcin_w, fcin_b, hA);
  for (int l = 0; l < 4; ++l) {
    k_prep<<<4096, 256, 0, stream>>>(wr + (size_t)l * 8388608,
                                     wi + (size_t)l * 8388608, Br, Bi);
    k_dft_y<<<2048, 256, 0, stream>>>(hA, A1);
    k_dft_x<<<dim3(16, 16, 2), 256, 0, stream>>>(A1, Ar, Ai);
    k_asplit<<<128, 256, 0, stream>>>(Ar, Ai, Ap);
    k_bsplit<<<512, 256, 0, stream>>>(Br, Bi, Bf);
    k_gemm_mfma<<<512, 256, 0, stream>>>(Ap, Bf, Cp, Pz1);
    k_ifft_y<<<256, 256, 0, stream>>>(Cp, Pz1, A1);   // A1 now holds T
    k_layer_out<<<2048, 256, 0, stream>>>(hA, A1, ww + (size_t)l * 4096,
                                          wb + (size_t)l * 64, hA);
  }
  k_final<<<2048, 256, 0, stream>>>(hA, fc1_w, fc1_b, fc2_w, fc2_b, out);
}